// Round 10
// baseline (489.566 us; speedup 1.0000x reference)
//
#include <hip/hip_runtime.h>
#include <cstddef>

static constexpr int N_NODES = 50000;
static constexpr int N_EDGES = 400000;
static constexpr int D = 256;
static constexpr int R = 2;
static constexpr int M_PAD = 50048;   // 391 * 128
static constexpr int CAP = 32;
static constexpr int NSEG = N_NODES * R;

typedef _Float16 f16x8 __attribute__((ext_vector_type(8)));
typedef float f32x4 __attribute__((ext_vector_type(4)));

__device__ __forceinline__ unsigned short f2h(float f) {
    _Float16 h = (_Float16)f;
    return *(unsigned short*)&h;
}
__device__ __forceinline__ float h2f(unsigned short u) {
    _Float16 h = *(_Float16*)&u;
    return (float)h;
}

#define GLOAD16(g, l)                                                          \
    __builtin_amdgcn_global_load_lds(                                          \
        (const __attribute__((address_space(1))) void*)(g),                    \
        (__attribute__((address_space(3))) void*)(l), 16, 0, 0)

// ===========================================================================
// f16x2 split-MFMA GEMM (stage-1), R9-verified math, now 2-phase pipelined:
// double-buffered LDS; next tile's global loads issued BEFORE current tile's
// MFMA (T3 minimum); A regs loaded early, split+ds_write late (T14).
// ===========================================================================
struct SSlab { const float* x; int xstr; int kstart; int mload; };
struct SArgs {
    SSlab sl[4];
    int nslab;
    const unsigned short* wt;   // 2 f16 planes, plane stride 256*Ktot
    int Ktot;
    int M;
    const float* bias;
    void* out;
};

template<int ACT>
__global__ __launch_bounds__(256, 2)
void sgemm(SArgs a) {
    __shared__ unsigned short As[2][2][128 * 32];   // [dbuf][plane]
    __shared__ unsigned short Bs[2][2][128 * 32];
    const int tid  = threadIdx.x;
    const int wave = tid >> 6, lane = tid & 63;
    const int wm = wave >> 1, wn = wave & 1;
    const int row0 = blockIdx.x * 128;
    const int n0   = blockIdx.y * 128;

    const int arow  = tid >> 1;
    const int ahalf = tid & 1;
    const int br_   = tid >> 2;
    const int bg_   = tid & 3;

    const int gk   = lane >> 4;
    const int frow = lane & 15;
    const int fslot = (gk ^ ((frow >> 1) & 3)) << 3;

    const int NT = a.Ktot / 32;
    float ev[16];

    auto loadA = [&](int t) {
        const int ks = t * 32;
        int s = a.nslab - 1;
        while (s > 0 && ks < a.sl[s].kstart) --s;
        const int gr = row0 + arow;
        if (gr < a.sl[s].mload) {
            const float* ap = a.sl[s].x + (size_t)gr * a.sl[s].xstr
                              + (ks - a.sl[s].kstart) + ahalf * 16;
            *(float4*)&ev[0]  = ((const float4*)ap)[0];
            *(float4*)&ev[4]  = ((const float4*)ap)[1];
            *(float4*)&ev[8]  = ((const float4*)ap)[2];
            *(float4*)&ev[12] = ((const float4*)ap)[3];
        } else {
            #pragma unroll
            for (int j = 0; j < 16; ++j) ev[j] = 0.f;
        }
    };
    auto stageB = [&](int buf, int t) {
        const int ks = t * 32;
        #pragma unroll
        for (int p = 0; p < 2; ++p) {
            #pragma unroll
            for (int q = 0; q < 2; ++q) {
                const int r = q * 64 + br_;
                const int gsrc = (bg_ ^ ((r >> 1) & 3)) << 3;
                GLOAD16(a.wt + (size_t)p * 256 * a.Ktot + (size_t)(n0 + r) * a.Ktot + ks + gsrc,
                        &Bs[buf][p][(q * 64 + wave * 16) * 32]);
            }
        }
    };
    auto writeA = [&](int buf) {
        const int sswz = (arow >> 1) & 3;
        #pragma unroll
        for (int g = 0; g < 2; ++g) {
            union { f16x8 v; _Float16 h[8]; } p1, p2;
            #pragma unroll
            for (int j = 0; j < 8; ++j) {
                const float v = ev[g * 8 + j];
                const _Float16 h1 = (_Float16)v;
                const float r1 = (v - (float)h1) * 2048.0f;
                p1.h[j] = h1; p2.h[j] = (_Float16)r1;
            }
            const int slot = ((ahalf * 2 + g) ^ sswz) << 3;
            *(f16x8*)&As[buf][0][arow * 32 + slot] = p1.v;
            *(f16x8*)&As[buf][1][arow * 32 + slot] = p2.v;
        }
    };

    f32x4 acc0[4][4] = {};
    f32x4 accC[4][4] = {};

    // prologue: fill buffer 0
    loadA(0);
    stageB(0, 0);
    writeA(0);
    __syncthreads();

    for (int t = 0; t < NT; ++t) {
        const int cur = t & 1, nxt = cur ^ 1;
        if (t + 1 < NT) { loadA(t + 1); stageB(nxt, t + 1); }   // issue early

        f16x8 bq[4][2];
        #pragma unroll
        for (int n = 0; n < 4; ++n) {
            const int rr = wn * 64 + n * 16 + frow;
            #pragma unroll
            for (int p = 0; p < 2; ++p)
                bq[n][p] = *(const f16x8*)&Bs[cur][p][rr * 32 + fslot];
        }
        #pragma unroll
        for (int m = 0; m < 4; ++m) {
            const int rr = wm * 64 + m * 16 + frow;
            const f16x8 a1 = *(const f16x8*)&As[cur][0][rr * 32 + fslot];
            const f16x8 a2 = *(const f16x8*)&As[cur][1][rr * 32 + fslot];
            #pragma unroll
            for (int n = 0; n < 4; ++n) {
                acc0[m][n] = __builtin_amdgcn_mfma_f32_16x16x32_f16(a1, bq[n][0], acc0[m][n], 0, 0, 0);
                accC[m][n] = __builtin_amdgcn_mfma_f32_16x16x32_f16(a1, bq[n][1], accC[m][n], 0, 0, 0);
                accC[m][n] = __builtin_amdgcn_mfma_f32_16x16x32_f16(a2, bq[n][0], accC[m][n], 0, 0, 0);
            }
        }
        __syncthreads();                         // drains next-tile loads (landed under MFMA)
        if (t + 1 < NT) { writeA(nxt); __syncthreads(); }   // write-late A split
    }

    const int erow = (lane >> 4) * 4;
    const int ecol = lane & 15;
    #pragma unroll
    for (int m = 0; m < 4; ++m) {
        #pragma unroll
        for (int r = 0; r < 4; ++r) {
            const int grow = row0 + wm * 64 + m * 16 + erow + r;
            if (grow >= a.M) continue;
            #pragma unroll
            for (int n = 0; n < 4; ++n) {
                const int gcol = n0 + wn * 64 + n * 16 + ecol;
                float v = acc0[m][n][r] + accC[m][n][r] * (1.0f / 2048.0f) + a.bias[gcol];
                if (ACT == 1) {
                    const float scale = 1.0507009873554804934f;
                    const float alpha = 1.6732632423543772848f;
                    v = (v > 0.f) ? scale * v : scale * alpha * (expf(v) - 1.f);
                }
                ((float*)a.out)[(size_t)grow * 256 + gcol] = v;
            }
        }
    }
}

// ===========================================================================
// Unified f16 MFMA GEMM (R9-verified math), 2-phase pipelined like sgemm.
// A32: A fp32 reg-staged (load early / split+ds_write late).
// EZ: expert from blockIdx.z.  PERM: permuted row gather/scatter.
// ===========================================================================
struct HSlab { const void* x; int xstr; int kstart; };
struct HArgs {
    HSlab sl[3];
    int nslab;
    const unsigned short* wt;
    int Ktot, M;
    const float* bias;
    const int* sel;
    const int* perm;
    const int* c01;
    void* out;
    int ldc;
};

template<int ACT, bool MASK, bool SELB, bool OUTF16, bool A32, bool EZ, bool PERM>
__global__ __launch_bounds__(256, 2)
void hgemm(HArgs a) {
    __shared__ unsigned short As[2][128 * 64];
    __shared__ unsigned short Bs[2][128 * 64];
    const int tid  = threadIdx.x;
    const int wave = tid >> 6, lane = tid & 63;
    const int wm = wave >> 1, wn = wave & 1;
    const int row0 = blockIdx.x * 128;
    const int n0   = blockIdx.y * 128;
    const int ex   = EZ ? (int)blockIdx.z : 0;
    const unsigned short* wt = a.wt + (size_t)ex * 65536;
    const float* bias = a.bias + ex * 256;

    int cntE = 0, base = 0;
    if (PERM) {
        const int c0 = a.c01[0];
        cntE = (ex == 0) ? c0 : a.M - c0;
        base = (ex == 0) ? 0 : c0;
        if (row0 >= cntE) return;
    }

    const int srow = lane >> 3;
    const int scol = ((lane & 7) ^ (lane >> 3)) << 3;
    const int arow  = tid >> 1;
    const int ahalf = tid & 1;

    const int NT = a.Ktot / 64;
    float ev[32];

    auto loadA32 = [&](int t) {
        const int k0 = t * 64;
        int s = a.nslab - 1;
        while (s > 0 && k0 < a.sl[s].kstart) --s;
        const float* xp = (const float*)a.sl[s].x;
        const float* ap = xp + (size_t)(row0 + arow) * a.sl[s].xstr
                          + (k0 - a.sl[s].kstart) + ahalf * 32;
        #pragma unroll
        for (int q = 0; q < 8; ++q)
            *(float4*)&ev[q * 4] = ((const float4*)ap)[q];
    };
    auto stageA = [&](int buf, int t) {    // !A32
        const int k0 = t * 64;
        int s = a.nslab - 1;
        while (s > 0 && k0 < a.sl[s].kstart) --s;
        const unsigned short* xp = (const unsigned short*)a.sl[s].x;
        const int kloc = k0 - a.sl[s].kstart;
        const int xstr = a.sl[s].xstr;
        #pragma unroll
        for (int i = 0; i < 4; ++i) {
            const int r = wave * 32 + i * 8;
            int lr = row0 + r + srow;
            if (PERM) lr = a.perm[base + (lr < cntE ? lr : cntE - 1)];
            GLOAD16(xp + (size_t)lr * xstr + kloc + scol, &As[buf][r * 64]);
        }
    };
    auto stageB = [&](int buf, int t) {
        const int k0 = t * 64;
        #pragma unroll
        for (int i = 0; i < 4; ++i) {
            const int r = wave * 32 + i * 8;
            GLOAD16(wt + (size_t)(n0 + r + srow) * a.Ktot + k0 + scol, &Bs[buf][r * 64]);
        }
    };
    auto writeA32 = [&](int buf) {
        #pragma unroll
        for (int gi = 0; gi < 4; ++gi) {
            const int sgr = ahalf * 4 + gi;
            union { f16x8 v; _Float16 h[8]; } pk;
            #pragma unroll
            for (int j = 0; j < 8; ++j) pk.h[j] = (_Float16)ev[gi * 8 + j];
            *(f16x8*)&As[buf][arow * 64 + ((sgr ^ (arow & 7)) << 3)] = pk.v;
        }
    };

    f32x4 acc[4][4] = {};

    // prologue
    if (A32) loadA32(0); else stageA(0, 0);
    stageB(0, 0);
    if (A32) writeA32(0);
    __syncthreads();

    for (int t = 0; t < NT; ++t) {
        const int cur = t & 1, nxt = cur ^ 1;
        if (t + 1 < NT) {
            if (A32) loadA32(t + 1); else stageA(nxt, t + 1);
            stageB(nxt, t + 1);
        }

        #pragma unroll
        for (int kk = 0; kk < 2; ++kk) {
            const int gkk = kk * 4 + (lane >> 4);
            f16x8 af[4], bfr[4];
            #pragma unroll
            for (int m = 0; m < 4; ++m) {
                const int rr = wm * 64 + m * 16 + (lane & 15);
                af[m] = *(const f16x8*)&As[cur][rr * 64 + ((gkk ^ (rr & 7)) << 3)];
            }
            #pragma unroll
            for (int n = 0; n < 4; ++n) {
                const int rr = wn * 64 + n * 16 + (lane & 15);
                bfr[n] = *(const f16x8*)&Bs[cur][rr * 64 + ((gkk ^ (rr & 7)) << 3)];
            }
            #pragma unroll
            for (int m = 0; m < 4; ++m)
                #pragma unroll
                for (int n = 0; n < 4; ++n)
                    acc[m][n] = __builtin_amdgcn_mfma_f32_16x16x32_f16(
                        af[m], bfr[n], acc[m][n], 0, 0, 0);
        }
        __syncthreads();
        if (A32 && t + 1 < NT) { writeA32(nxt); __syncthreads(); }
    }

    const int erow = (lane >> 4) * 4;
    const int ecol = lane & 15;
    #pragma unroll
    for (int m = 0; m < 4; ++m) {
        #pragma unroll
        for (int r = 0; r < 4; ++r) {
            const int grow = row0 + wm * 64 + m * 16 + erow + r;
            if (PERM) { if (grow >= cntE) continue; }
            else      { if (grow >= a.M) continue; }
            const int orow = PERM ? a.perm[base + grow] : grow;
            int sv = 0;
            if (MASK || SELB) sv = a.sel[orow];
            #pragma unroll
            for (int n = 0; n < 4; ++n) {
                const int gcol = n0 + wn * 64 + n * 16 + ecol;
                const float b = SELB ? a.bias[sv * 256 + gcol] : bias[gcol];
                float v = acc[m][n][r] + b;
                if (ACT == 2) v = (v >= 0.f) ? v : 0.01f * v;
                if (MASK && sv != ex) v = 0.f;
                const size_t oidx = (size_t)orow * a.ldc + ((EZ && !PERM) ? ex * 256 : 0) + gcol;
                if (OUTF16) ((unsigned short*)a.out)[oidx] = f2h(v);
                else        ((float*)a.out)[oidx] = v;
            }
        }
    }
}

// ===========================================================================
// bucket-CSR build (verified)
// ===========================================================================
__global__ __launch_bounds__(256)
void csr_build(const int* __restrict__ ei, const int* __restrict__ et,
               int* cnt, int* slots) {
    const int e = blockIdx.x * 256 + threadIdx.x;
    if (e >= N_EDGES) return;
    const int src = ei[e];
    const int dst = ei[N_EDGES + e];
    const int seg = dst * R + et[e];
    const int slot = atomicAdd(&cnt[seg], 1);
    if (slot < CAP) slots[(size_t)seg * CAP + slot] = src;
}

// fp32 aggregate (verified; 2-way unrolled gather)
__global__ __launch_bounds__(256)
void aggregate(const float* __restrict__ X, const int* __restrict__ cnt,
               const int* __restrict__ slots, float* __restrict__ Ab,
               int seg0, int nseg) {
    const int w = blockIdx.x * 4 + (threadIdx.x >> 6);
    if (w >= nseg) return;
    const int lane = threadIdx.x & 63;
    const int s = seg0 + w;
    const int m = min(cnt[s], CAP);
    const int* sl = slots + (size_t)s * CAP;
    float4 acc = make_float4(0.f, 0.f, 0.f, 0.f);
    int i = 0;
    for (; i + 1 < m; i += 2) {
        const float4 v0 = *(const float4*)(X + (size_t)sl[i] * 256 + lane * 4);
        const float4 v1 = *(const float4*)(X + (size_t)sl[i + 1] * 256 + lane * 4);
        acc.x += v0.x + v1.x; acc.y += v0.y + v1.y;
        acc.z += v0.z + v1.z; acc.w += v0.w + v1.w;
    }
    if (i < m) {
        const float4 v = *(const float4*)(X + (size_t)sl[i] * 256 + lane * 4);
        acc.x += v.x; acc.y += v.y; acc.z += v.z; acc.w += v.w;
    }
    const float inv = (m > 0) ? 1.0f / (float)m : 0.0f;
    acc.x *= inv; acc.y *= inv; acc.z *= inv; acc.w *= inv;
    *(float4*)(Ab + (size_t)(w >> 1) * 512 + (w & 1) * 256 + lane * 4) = acc;
}

// f16 aggregate (verified; 2-way unrolled gather)
__global__ __launch_bounds__(256)
void agg_h(const unsigned short* __restrict__ Xh, const int* __restrict__ cnt,
           const int* __restrict__ slots, unsigned short* __restrict__ Abh) {
    const int w = blockIdx.x * 4 + (threadIdx.x >> 6);
    if (w >= NSEG) return;
    const int lane = threadIdx.x & 63;
    const int m = min(cnt[w], CAP);
    const int* sl = slots + (size_t)w * CAP;
    float ac[4] = {};
    int i = 0;
    for (; i + 1 < m; i += 2) {
        const ushort4 v0 = *(const ushort4*)(Xh + (size_t)sl[i] * 256 + lane * 4);
        const ushort4 v1 = *(const ushort4*)(Xh + (size_t)sl[i + 1] * 256 + lane * 4);
        ac[0] += h2f(v0.x) + h2f(v1.x); ac[1] += h2f(v0.y) + h2f(v1.y);
        ac[2] += h2f(v0.z) + h2f(v1.z); ac[3] += h2f(v0.w) + h2f(v1.w);
    }
    if (i < m) {
        const ushort4 v = *(const ushort4*)(Xh + (size_t)sl[i] * 256 + lane * 4);
        ac[0] += h2f(v.x); ac[1] += h2f(v.y); ac[2] += h2f(v.z); ac[3] += h2f(v.w);
    }
    const float inv = (m > 0) ? 1.0f / (float)m : 0.0f;
    ushort4 o = make_ushort4(f2h(ac[0] * inv), f2h(ac[1] * inv),
                             f2h(ac[2] * inv), f2h(ac[3] * inv));
    *(ushort4*)(Abh + (size_t)(w >> 1) * 512 + (w & 1) * 256 + lane * 4) = o;
}

// ===========================================================================
// Exact gate pipeline (verified R8/R9)
// ===========================================================================
__global__ __launch_bounds__(256)
void fold1(const float* __restrict__ W_root, const float* __restrict__ W_rel,
           const float* __restrict__ b_rg, const float* __restrict__ wg,
           float* __restrict__ wfold, float* __restrict__ c3) {
    const int idx = blockIdx.x * 256 + threadIdx.x;
    if (idx < 1536) {
        const int d = idx / 6, jj = idx % 6, c = jj >> 1, j = jj & 1;
        const float* row = (c == 0) ? W_root + (size_t)d * 256
                                    : W_rel + (size_t)(c - 1) * 65536 + (size_t)d * 256;
        float s = 0.f;
        for (int e = 0; e < 256; ++e) s += row[e] * wg[e * 2 + j];
        wfold[idx] = s;
    } else if (idx < 1538) {
        const int j = idx - 1536;
        float s = 0.f;
        for (int e = 0; e < 256; ++e) s += b_rg[e] * wg[e * 2 + j];
        c3[j] = s;
    }
}

__global__ __launch_bounds__(256)
void fold2(const float* __restrict__ W_root, const float* __restrict__ W_rel,
           const float* __restrict__ b_rg, const float* __restrict__ wfold,
           float* __restrict__ W6, float* __restrict__ cb) {
    const int idx = blockIdx.x * 256 + threadIdx.x;
    if (idx < 4608) {
        const int k = idx / 6, j = idx % 6;
        const float* row = (k < 256) ? W_root + (size_t)k * 256
                                     : W_rel + (size_t)(k - 256) * 256;
        float s = 0.f;
        for (int d = 0; d < 256; ++d) s += row[d] * wfold[d * 6 + j];
        W6[idx] = s;
    } else if (idx < 4614) {
        const int j = idx - 4608;
        float s = 0.f;
        for (int d = 0; d < 256; ++d) s += b_rg[d] * wfold[d * 6 + j];
        cb[j] = s;
    }
}

__global__ __launch_bounds__(256)
void vu_kernel(const float* __restrict__ X1, const float* __restrict__ Ab,
               const float* __restrict__ W6, float* __restrict__ VU, int M) {
    __shared__ float wl[768 * 6];
    for (int i = threadIdx.x; i < 768 * 6; i += 256) wl[i] = W6[i];
    __syncthreads();
    const int wave = threadIdx.x >> 6, lane = threadIdx.x & 63;
    const int n = blockIdx.x * 4 + wave;
    if (n >= M) return;
    const float4 xv = ((const float4*)(X1 + (size_t)n * 256))[lane];
    const float4 a0 = ((const float4*)(Ab + (size_t)n * 512))[lane];
    const float4 a1 = ((const float4*)(Ab + (size_t)n * 512))[lane + 64];
    const float xa[12] = {xv.x, xv.y, xv.z, xv.w, a0.x, a0.y, a0.z, a0.w,
                          a1.x, a1.y, a1.z, a1.w};
    float z[6] = {};
    #pragma unroll
    for (int t = 0; t < 3; ++t)
        #pragma unroll
        for (int i = 0; i < 4; ++i) {
            const int k = t * 256 + lane * 4 + i;
            #pragma unroll
            for (int j = 0; j < 6; ++j) z[j] = fmaf(xa[t * 4 + i], wl[k * 6 + j], z[j]);
        }
    #pragma unroll
    for (int off = 32; off; off >>= 1)
        #pragma unroll
        for (int j = 0; j < 6; ++j) z[j] += __shfl_down(z[j], off, 64);
    if (lane == 0) {
        #pragma unroll
        for (int j = 0; j < 6; ++j) VU[(size_t)n * 6 + j] = z[j];
    }
}

__global__ __launch_bounds__(256)
void u_gate(const float* __restrict__ VU, const int* __restrict__ cnt,
            const int* __restrict__ slots, const float* __restrict__ cb,
            const float* __restrict__ c3, int* __restrict__ sel, int M) {
    const int n = blockIdx.x * 256 + threadIdx.x;
    if (n >= M) return;
    float z0 = VU[(size_t)n * 6 + 0] + cb[0] + c3[0];
    float z1 = VU[(size_t)n * 6 + 1] + cb[1] + c3[1];
    #pragma unroll
    for (int r = 0; r < 2; ++r) {
        const int seg = n * 2 + r;
        const int m = min(cnt[seg], CAP);
        if (m > 0) {
            const int* sl = slots + (size_t)seg * CAP;
            float s0 = 0.f, s1 = 0.f;
            for (int i = 0; i < m; ++i) {
                const int src = sl[i];
                s0 += VU[(size_t)src * 6 + 2 + 2 * r];
                s1 += VU[(size_t)src * 6 + 3 + 2 * r];
            }
            const float inv = 1.0f / (float)m;
            z0 += s0 * inv + cb[2 + 2 * r];
            z1 += s1 * inv + cb[3 + 2 * r];
        }
    }
    sel[n] = (z1 > z0) ? 1 : 0;
}

// expert permutation: expert0 list grows from 0, expert1 from N_NODES down
__global__ __launch_bounds__(256)
void build_perm(const int* __restrict__ sel, int* __restrict__ perm, int* c01) {
    const int n = blockIdx.x * 256 + threadIdx.x;
    if (n >= N_NODES) return;
    if (sel[n] == 0) perm[atomicAdd(&c01[0], 1)] = n;
    else             perm[N_NODES - 1 - atomicAdd(&c01[1], 1)] = n;
}

// ===========================================================================
// weight prep
// ===========================================================================
__global__ __launch_bounds__(256)
void wconv2(const float* __restrict__ src, unsigned short* __restrict__ dst) {
    const int i = blockIdx.x * 256 + threadIdx.x;   // 256x256
    const int k = i >> 8, n = i & 255;
    const float v = src[i];
    const _Float16 h1 = (_Float16)v;
    const float r1 = (v - (float)h1) * 2048.0f;
    dst[(size_t)n * 256 + k] = f2h(v);
    dst[65536 + (size_t)n * 256 + k] = f2h(r1);
}

struct WJH { const float* src[8]; unsigned short* dst[8]; int stride[8]; int koff[8]; };
__global__ __launch_bounds__(256)
void wconv_h(WJH j) {
    const int job = blockIdx.y;
    const int i = blockIdx.x * 256 + threadIdx.x;
    const int k = i >> 8, n = i & 255;
    j.dst[job][(size_t)n * j.stride[job] + j.koff[job] + k] = f2h(j.src[job][i]);
}

// ===========================================================================
extern "C" void kernel_launch(void* const* d_in, const int* in_sizes, int n_in,
                              void* d_out, int out_size, void* d_ws, size_t ws_size,
                              hipStream_t stream) {
    const float* des    = (const float*)d_in[0];
    const float* twt    = (const float*)d_in[1];
    const float* nump   = (const float*)d_in[2];
    const float* catp   = (const float*)d_in[3];
    const int*   ei     = (const int*)d_in[4];
    const int*   et     = (const int*)d_in[5];
    const float* W_in   = (const float*)d_in[6];
    const float* b_in   = (const float*)d_in[7];
    const float* W_rel  = (const float*)d_in[8];
    const float* W_root = (const float*)d_in[9];
    const float* b_rg   = (const float*)d_in[10];
    const float* w_gate = (const float*)d_in[11];
    const float* We1    = (const float*)d_in[12];
    const float* be1    = (const float*)d_in[13];
    const float* We2    = (const float*)d_in[14];
    const float* be2    = (const float*)d_in[15];

    // ---- workspace (~196 MB; layout identical to R9-verified) ----
    char* ws = (char*)d_ws;
    size_t off = 0;
    auto alloc = [&](size_t bytes) { char* p = ws + off; off += (bytes + 255) & ~(size_t)255; return p; };
    float* X1f  = (float*)alloc((size_t)M_PAD * 256 * 4);      // 51.25 MB
    char*  regA = alloc((size_t)M_PAD * 512 * 4);              // 102.5 MB: Ab1f | Ab2h , H
    unsigned short* X2h = (unsigned short*)alloc((size_t)M_PAD * 256 * 2);  // 25.6 MB
    float* VU   = (float*)alloc((size_t)N_NODES * 6 * 4);
    int*   cnt  = (int*)alloc((size_t)NSEG * 4);
    int*   sel  = (int*)alloc((size_t)N_NODES * 4);
    int*   perm = (int*)alloc((size_t)N_NODES * 4);
    int*   c01  = (int*)alloc(256);
    int*   slots= (int*)alloc((size_t)NSEG * CAP * 4);         // 12.8 MB
    unsigned short* wt_in2 = (unsigned short*)alloc((size_t)2 * 65536 * 2);
    unsigned short* wt_rg  = (unsigned short*)alloc((size_t)256 * 768 * 2);
    unsigned short* wt_e1  = (unsigned short*)alloc((size_t)2 * 65536 * 2);
    unsigned short* wt_e2  = (unsigned short*)alloc((size_t)2 * 65536 * 2);
    float* wfold = (float*)alloc(256 * 6 * 4);
    float* c3    = (float*)alloc(8);
    float* W6    = (float*)alloc(768 * 6 * 4);
    float* cb    = (float*)alloc(24);

    float* Ab1f = (float*)regA;                                   // fp32, layer-1
    unsigned short* Ab2h = (unsigned short*)regA;                 // f16, layer-2 (Ab1f dead)
    unsigned short* H    = (unsigned short*)(regA + (size_t)M_PAD * 512 * 2); // f16 [n][256]
    unsigned short* X3h  = (unsigned short*)X1f;                  // f16, after X1f dead

    const dim3 blk(256);

    // ---- prep ----
    hipMemsetAsync(cnt, 0, (size_t)NSEG * 4, stream);
    hipMemsetAsync(c01, 0, 8, stream);
    csr_build<<<(N_EDGES + 255) / 256, blk, 0, stream>>>(ei, et, cnt, slots);
    wconv2<<<256, blk, 0, stream>>>(W_in, wt_in2);
    {
        WJH j{};
        j.src[0] = W_root;         j.dst[0] = wt_rg;         j.stride[0] = 768; j.koff[0] = 0;
        j.src[1] = W_rel;          j.dst[1] = wt_rg;         j.stride[1] = 768; j.koff[1] = 256;
        j.src[2] = W_rel + 65536;  j.dst[2] = wt_rg;         j.stride[2] = 768; j.koff[2] = 512;
        j.src[3] = We1;            j.dst[3] = wt_e1;         j.stride[3] = 256; j.koff[3] = 0;
        j.src[4] = We1 + 65536;    j.dst[4] = wt_e1 + 65536; j.stride[4] = 256; j.koff[4] = 0;
        j.src[5] = We2;            j.dst[5] = wt_e2;         j.stride[5] = 256; j.koff[5] = 0;
        j.src[6] = We2 + 65536;    j.dst[6] = wt_e2 + 65536; j.stride[6] = 256; j.koff[6] = 0;
        wconv_h<<<dim3(256, 7), blk, 0, stream>>>(j);
    }
    fold1<<<7, blk, 0, stream>>>(W_root, W_rel, b_rg, w_gate, wfold, c3);
    fold2<<<19, blk, 0, stream>>>(W_root, W_rel, b_rg, wfold, W6, cb);

    // ---- stage 1: X1f = selu(concat @ W_in + b_in)  [f16x2, fp32-grade] ----
    {
        SArgs g{};
        g.sl[0] = {des,  128, 0,   N_NODES};
        g.sl[1] = {twt,  64,  128, N_NODES};
        g.sl[2] = {nump, 32,  192, N_NODES};
        g.sl[3] = {catp, 32,  224, N_NODES};
        g.nslab = 4; g.wt = wt_in2; g.Ktot = 256; g.M = N_NODES;
        g.bias = b_in; g.out = X1f;
        hipLaunchKernelGGL((sgemm<1>), dim3(391, 2), blk, 0, stream, g);
    }

    // ---- layer-1 aggregate (fp32, full M) ----
    aggregate<<<(NSEG + 3) / 4, blk, 0, stream>>>(X1f, cnt, slots, Ab1f, 0, NSEG);

    // ---- exact gate pipeline (fp32) ----
    vu_kernel<<<(N_NODES + 3) / 4, blk, 0, stream>>>(X1f, Ab1f, W6, VU, N_NODES);
    u_gate<<<(N_NODES + 255) / 256, blk, 0, stream>>>(VU, cnt, slots, cb, c3, sel, N_NODES);
    build_perm<<<(N_NODES + 255) / 256, blk, 0, stream>>>(sel, perm, c01);

    // ---- layer 1: X2h = [X1f|Ab1f] @ W_all + b   (f16 MFMA, fp32-cvt A) ----
    {
        HArgs g{};
        g.sl[0] = {X1f,        256, 0};
        g.sl[1] = {Ab1f,       512, 256};
        g.sl[2] = {Ab1f + 256, 512, 512};
        g.nslab = 3; g.wt = wt_rg; g.Ktot = 768; g.M = N_NODES;
        g.bias = b_rg; g.out = X2h; g.ldc = 256;
        hipLaunchKernelGGL((hgemm<0, false, false, true, true, false, false>),
                           dim3(391, 2), blk, 0, stream, g);
    }

    // ---- layer-2 aggregate (f16) ----
    agg_h<<<(NSEG + 3) / 4, blk, 0, stream>>>(X2h, cnt, slots, Ab2h);

    // ---- layer 2: X3h = [X2h|Ab2h] @ W_all + b   (f16 direct) ----
    {
        HArgs g{};
        g.sl[0] = {X2h,        256, 0};
        g.sl[1] = {Ab2h,       512, 256};
        g.sl[2] = {Ab2h + 256, 512, 512};
        g.nslab = 3; g.wt = wt_rg; g.Ktot = 768; g.M = N_NODES;
        g.bias = b_rg; g.out = X3h; g.ldc = 256;
        hipLaunchKernelGGL((hgemm<0, false, false, true, false, false, false>),
                           dim3(391, 2), blk, 0, stream, g);
    }

    // ---- MoE h1, selected expert only (permuted gather/scatter) ----
    {
        HArgs g{};
        g.sl[0] = {X3h, 256, 0};
        g.nslab = 1; g.wt = wt_e1; g.Ktot = 256; g.M = N_NODES;
        g.bias = be1; g.perm = perm; g.c01 = c01; g.out = H; g.ldc = 256;
        hipLaunchKernelGGL((hgemm<2, false, false, true, false, true, true>),
                           dim3(391, 2, 2), blk, 0, stream, g);
    }

    // ---- MoE out: d_out[n] = H[n] @ We2[sel[n]] + be2[sel[n]]  (permuted) ----
    {
        HArgs g{};
        g.sl[0] = {H, 256, 0};
        g.nslab = 1; g.wt = wt_e2; g.Ktot = 256; g.M = N_NODES;
        g.bias = be2; g.perm = perm; g.c01 = c01; g.out = d_out; g.ldc = 256;
        hipLaunchKernelGGL((hgemm<0, false, false, false, false, true, true>),
                           dim3(391, 2, 2), blk, 0, stream, g);
    }
}